// Round 1
// baseline (153.865 us; speedup 1.0000x reference)
//
#include <hip/hip_runtime.h>
#include <hip/hip_bf16.h>

// Sparse self-attention: dense attention within each residue class (mod 4)
// + 7-wide local window (duplicated dense entries, logit += ln2) + OOB window
// slots contributing exp(0) to the denominator.

#define BATCH 2
#define LSEQ  4096
#define DMODEL 512
#define NH    8
#define DHEAD 64
#define RATE  4
#define NQ    1024      // valid query class-rows (t < 4096)
#define NPAD  1088      // key rows padded to 17*64 (valid keys: 0..1024, m=1024 is the zero key)
#define SCALE 0.125f
#define LN2F  0.6931471805599453f

typedef __bf16 bf16x8 __attribute__((ext_vector_type(8)));
typedef __attribute__((ext_vector_type(4))) float f32x4;
typedef unsigned short u16;
typedef unsigned int u32;

__device__ __forceinline__ u16 f2bf(float f) {
    u32 u = __float_as_uint(f);
    u += 0x7fffu + ((u >> 16) & 1u);   // RNE, inputs finite
    return (u16)(u >> 16);
}

// ---------------------------------------------------------------------------
// Projection: out[t][j] = sum_k x[t][k] * W[k][j], written as bf16 into
// [b][h][r][n][64] with n = t/4, r = t%4.  M = 8192 (b*4096), N = 512, K = 512.
// Tile: BM=128, BN=64 (one head), BK=32; 4 waves, each 32x64 output.
// ---------------------------------------------------------------------------
__global__ __launch_bounds__(256) void proj_kernel(
    const float* __restrict__ x,
    const float* __restrict__ Wq, const float* __restrict__ Wk, const float* __restrict__ Wv,
    u16* __restrict__ Qb, u16* __restrict__ Kb, u16* __restrict__ Vb)
{
    const int mz = blockIdx.z;
    const float* W = (mz == 0) ? Wq : (mz == 1) ? Wk : Wv;
    u16* Ob        = (mz == 0) ? Qb : (mz == 1) ? Kb : Vb;

    const int m0  = blockIdx.x * 128;
    const int h   = blockIdx.y;                // N-tile == head
    const int tid = threadIdx.x;
    const int w   = tid >> 6;
    const int l   = tid & 63;
    const int lr  = l & 15, lh = l >> 4;

    __shared__ u16 As[128][40];   // [m][k], +8 pad (80B rows, 16B aligned)
    __shared__ u16 Bs[64][40];    // [n][k]  (B^T layout)

    f32x4 acc[2][4];
    const f32x4 fzero = {0.f, 0.f, 0.f, 0.f};
    #pragma unroll
    for (int i = 0; i < 2; ++i)
        #pragma unroll
        for (int j = 0; j < 4; ++j) acc[i][j] = fzero;

    for (int kt = 0; kt < 16; ++kt) {
        const int k0 = kt * 32;
        // stage A: 128x32 fp32 -> bf16
        {
            const int row  = tid >> 1;
            const int part = (tid & 1) * 16;
            const float* src = x + (size_t)(m0 + row) * DMODEL + k0 + part;
            u16* dst = &As[row][part];
            #pragma unroll
            for (int q4 = 0; q4 < 4; ++q4) {
                float4 v = *(const float4*)(src + q4 * 4);
                dst[q4*4+0] = f2bf(v.x); dst[q4*4+1] = f2bf(v.y);
                dst[q4*4+2] = f2bf(v.z); dst[q4*4+3] = f2bf(v.w);
            }
        }
        // stage B transposed: W[k0+kk][h*64+n] -> Bs[n][kk]
        #pragma unroll
        for (int rep = 0; rep < 2; ++rep) {
            const int idx = rep * 256 + tid;       // 0..511 float4 index
            const int kk  = idx >> 4;              // 0..31
            const int n4  = (idx & 15) * 4;        // 0..60
            float4 v = *(const float4*)(W + (size_t)(k0 + kk) * DMODEL + h * 64 + n4);
            Bs[n4+0][kk] = f2bf(v.x);
            Bs[n4+1][kk] = f2bf(v.y);
            Bs[n4+2][kk] = f2bf(v.z);
            Bs[n4+3][kk] = f2bf(v.w);
        }
        __syncthreads();

        bf16x8 af[2];
        #pragma unroll
        for (int i = 0; i < 2; ++i)
            af[i] = *(const bf16x8*)&As[w*32 + i*16 + lr][lh*8];
        #pragma unroll
        for (int j = 0; j < 4; ++j) {
            bf16x8 bfB = *(const bf16x8*)&Bs[j*16 + lr][lh*8];
            #pragma unroll
            for (int i = 0; i < 2; ++i)
                acc[i][j] = __builtin_amdgcn_mfma_f32_16x16x32_bf16(af[i], bfB, acc[i][j], 0, 0, 0);
        }
        __syncthreads();
    }

    // write out: C layout col=lane&15, row=(lane>>4)*4+reg  [verified m89]
    #pragma unroll
    for (int i = 0; i < 2; ++i) {
        #pragma unroll
        for (int j = 0; j < 4; ++j) {
            #pragma unroll
            for (int rr = 0; rr < 4; ++rr) {
                const int gm = m0 + w*32 + i*16 + lh*4 + rr;
                const int b  = gm >> 12;
                const int t  = gm & 4095;
                const int n  = t >> 2, r = t & 3;
                const int dk = j*16 + lr;
                const size_t oidx = ((((size_t)(b*NH + h))*RATE + r)*NPAD + n)*DHEAD + dk;
                Ob[oidx] = f2bf(acc[i][j][rr]);
            }
        }
    }
}

// ---------------------------------------------------------------------------
// Flash attention per (b,h,r) class: 64 queries/block, 17 key tiles of 64.
// ---------------------------------------------------------------------------
__global__ __launch_bounds__(256) void attn_kernel(
    const u16* __restrict__ Qb, const u16* __restrict__ Kb, const u16* __restrict__ Vb,
    float* __restrict__ out)
{
    const int g  = blockIdx.y;          // ((b*8+h)*4+r)
    const int b  = g >> 5;
    const int h  = (g >> 2) & 7;
    const int r  = g & 3;
    const int q0 = blockIdx.x * 64;
    const int tid = threadIdx.x;
    const int w  = tid >> 6;
    const int l  = tid & 63;
    const int lr = l & 15, lh = l >> 4;

    const u16* Qg = Qb + (size_t)g * NPAD * DHEAD;
    const u16* Kg = Kb + (size_t)g * NPAD * DHEAD;
    const u16* Vg = Vb + (size_t)g * NPAD * DHEAD;

    __shared__ u16 Ks[64][72];       // [m][k], +8 pad
    __shared__ u16 Vs[64][72];       // [dv][m] (V transposed), +8 pad
    __shared__ u16 Ps[4][16][72];    // per-wave P tile [qrow][m], +8 pad

    // Q fragments, hoisted (wave w owns query rows q0+w*16 .. +15)
    bf16x8 qa[2];
    {
        const u16* qrow = Qg + (size_t)(q0 + w*16 + lr) * DHEAD;
        qa[0] = *(const bf16x8*)(qrow + lh*8);
        qa[1] = *(const bf16x8*)(qrow + 32 + lh*8);
    }

    const f32x4 fzero = {0.f, 0.f, 0.f, 0.f};
    f32x4 o[4];
    #pragma unroll
    for (int j = 0; j < 4; ++j) o[j] = fzero;
    float Mrow[4], Lrow[4];
    #pragma unroll
    for (int rr = 0; rr < 4; ++rr) { Mrow[rr] = -1e30f; Lrow[rr] = 0.f; }

    for (int mt = 0; mt < 17; ++mt) {
        const int m0 = mt * 64;
        // stage K tile and transposed V tile
        #pragma unroll
        for (int rep = 0; rep < 2; ++rep) {
            const int cidx = rep * 256 + tid;    // 0..511
            const int row  = cidx >> 3;          // key row 0..63
            const int ch   = cidx & 7;           // 16B chunk
            *(bf16x8*)&Ks[row][ch*8] =
                *(const bf16x8*)(Kg + (size_t)(m0 + row) * DHEAD + ch*8);
            bf16x8 vv = *(const bf16x8*)(Vg + (size_t)(m0 + row) * DHEAD + ch*8);
            #pragma unroll
            for (int j2 = 0; j2 < 8; ++j2) {
                __bf16 e = vv[j2];
                Vs[ch*8 + j2][row] = *(const u16*)&e;
            }
        }
        __syncthreads();

        // S = Q K^T  (wave: 16 x 64)
        f32x4 s[4];
        #pragma unroll
        for (int ni = 0; ni < 4; ++ni) {
            s[ni] = fzero;
            #pragma unroll
            for (int kk = 0; kk < 2; ++kk) {
                bf16x8 kb = *(const bf16x8*)&Ks[ni*16 + lr][kk*32 + lh*8];
                s[ni] = __builtin_amdgcn_mfma_f32_16x16x32_bf16(qa[kk], kb, s[ni], 0, 0, 0);
            }
        }

        // scale + key mask + window doubling (logit += ln2 for |m-q|<=3)
        float sv[4][4];
        #pragma unroll
        for (int ni = 0; ni < 4; ++ni) {
            const int mg = m0 + ni*16 + lr;
            #pragma unroll
            for (int rr = 0; rr < 4; ++rr) {
                const int qg = q0 + w*16 + lh*4 + rr;
                float v = s[ni][rr] * SCALE;
                const int dd = mg - qg;
                if (mg > 1024)              v = -1e30f;
                else if (dd >= -3 && dd <= 3) v += LN2F;
                sv[ni][rr] = v;
            }
        }

        // per-row tile max (reduce across the 16 lanes of each row group)
        float alpha[4];
        #pragma unroll
        for (int rr = 0; rr < 4; ++rr) {
            float m_ = fmaxf(fmaxf(sv[0][rr], sv[1][rr]), fmaxf(sv[2][rr], sv[3][rr]));
            #pragma unroll
            for (int off = 1; off < 16; off <<= 1)
                m_ = fmaxf(m_, __shfl_xor(m_, off, 16));
            const float newM = fmaxf(Mrow[rr], m_);
            alpha[rr] = __expf(Mrow[rr] - newM);
            Mrow[rr]  = newM;
        }

        // P = exp(sv - M); row sums; write P (bf16) to LDS in C layout
        float tsum[4] = {0.f, 0.f, 0.f, 0.f};
        #pragma unroll
        for (int ni = 0; ni < 4; ++ni) {
            #pragma unroll
            for (int rr = 0; rr < 4; ++rr) {
                const float p = __expf(sv[ni][rr] - Mrow[rr]);
                tsum[rr] += p;
                Ps[w][lh*4 + rr][ni*16 + lr] = f2bf(p);
            }
        }
        #pragma unroll
        for (int rr = 0; rr < 4; ++rr) {
            float s_ = tsum[rr];
            #pragma unroll
            for (int off = 1; off < 16; off <<= 1)
                s_ += __shfl_xor(s_, off, 16);
            Lrow[rr] = Lrow[rr] * alpha[rr] + s_;
        }
        #pragma unroll
        for (int j = 0; j < 4; ++j)
            #pragma unroll
            for (int rr = 0; rr < 4; ++rr)
                o[j][rr] *= alpha[rr];

        // O += P V   (A = P from Ps, B = V from transposed Vs; same frag map)
        #pragma unroll
        for (int kk = 0; kk < 2; ++kk) {
            bf16x8 pa = *(const bf16x8*)&Ps[w][lr][kk*32 + lh*8];
            #pragma unroll
            for (int j = 0; j < 4; ++j) {
                bf16x8 vb = *(const bf16x8*)&Vs[j*16 + lr][kk*32 + lh*8];
                o[j] = __builtin_amdgcn_mfma_f32_16x16x32_bf16(pa, vb, o[j], 0, 0, 0);
            }
        }
        __syncthreads();
    }

    // epilogue: OOB window slots add coob * exp(0 - M) to the denominator
    #pragma unroll
    for (int rr = 0; rr < 4; ++rr) {
        const int qg = q0 + w*16 + lh*4 + rr;
        const int coob = (qg < 3 ? 3 - qg : 0) + (qg > 1021 ? qg - 1021 : 0);
        const float den = Lrow[rr] + (float)coob * __expf(-Mrow[rr]);
        const float inv = 1.0f / den;
        const int t = qg * 4 + r;
        float* orow = out + ((size_t)b * LSEQ + t) * DMODEL + h * DHEAD;
        #pragma unroll
        for (int j = 0; j < 4; ++j)
            orow[j*16 + lr] = o[j][rr] * inv;
    }
}

extern "C" void kernel_launch(void* const* d_in, const int* in_sizes, int n_in,
                              void* d_out, int out_size, void* d_ws, size_t ws_size,
                              hipStream_t stream) {
    const float* x  = (const float*)d_in[0];
    const float* Wq = (const float*)d_in[1];
    const float* Wk = (const float*)d_in[2];
    const float* Wv = (const float*)d_in[3];
    float* out = (float*)d_out;

    const size_t SZ = (size_t)BATCH * NH * RATE * NPAD * DHEAD;  // elems per tensor
    u16* Qb = (u16*)d_ws;
    u16* Kb = Qb + SZ;
    u16* Vb = Kb + SZ;

    // zero-fill gives the pad key rows (n >= 1024) their required zeros
    hipMemsetAsync(d_ws, 0, 3 * SZ * sizeof(u16), stream);

    dim3 gp(64, 8, 3);                 // 8192/128 M-tiles, 8 heads, q/k/v
    proj_kernel<<<gp, 256, 0, stream>>>(x, Wq, Wk, Wv, Qb, Kb, Vb);

    dim3 ga(16, 64);                   // 16 query tiles, 64 (b,h,r) groups
    attn_kernel<<<ga, 256, 0, stream>>>(Qb, Kb, Vb, out);
}

// Round 2
// 115.739 us; speedup vs baseline: 1.3294x; 1.3294x over previous
//
#include <hip/hip_runtime.h>
#include <hip/hip_bf16.h>

// Sparse self-attention: dense attention within each residue class (mod 4)
// + 7-wide local window (duplicated dense entries => logit += ln2) + OOB window
// slots contributing exp(0) to the denominator.
//
// This version: no online max (logits bounded -> fixed M=0), log2-space logits
// (0.125*log2e baked into Q), V pre-transposed by the projection kernel so the
// attention staging is fully vectorized.

#define BATCH 2
#define LSEQ  4096
#define DMODEL 512
#define NH    8
#define DHEAD 64
#define RATE  4
#define NQ    1024      // valid query class-rows (t < 4096)
#define NPAD  1088      // key rows padded to 17*64 (valid: 0..1024; m=1024 is the zero key)
#define QSCALE 0.18033688011112042f   // 0.125 * log2(e)

typedef __bf16 bf16x8 __attribute__((ext_vector_type(8)));
typedef __attribute__((ext_vector_type(4))) float f32x4;
typedef unsigned short u16;
typedef unsigned int u32;

__device__ __forceinline__ u16 f2bf(float f) {
    u32 u = __float_as_uint(f);
    u += 0x7fffu + ((u >> 16) & 1u);   // RNE, inputs finite
    return (u16)(u >> 16);
}

// ---------------------------------------------------------------------------
// Projection: out[t][j] = sum_k x[t][k] * W[k][j], bf16 out.
//   Q: [g][n][dk] scaled by 0.125*log2e        (g = ((b*8+h)*4+r), n = t/4)
//   K: [g][n][dk]
//   V: [g][dv][n]  (TRANSPOSED so attention can stage V^T with b128 copies)
// M = 8192 (b,t), N = 512, K = 512.  BM=128, BN=64 (one head), BK=32, 4 waves.
// ---------------------------------------------------------------------------
__global__ __launch_bounds__(256) void proj_kernel(
    const float* __restrict__ x,
    const float* __restrict__ Wq, const float* __restrict__ Wk, const float* __restrict__ Wv,
    u16* __restrict__ Qb, u16* __restrict__ Kb, u16* __restrict__ Vb)
{
    const int mz = blockIdx.z;
    const float* W = (mz == 0) ? Wq : (mz == 1) ? Wk : Wv;
    u16* Ob        = (mz == 0) ? Qb : (mz == 1) ? Kb : Vb;
    const float osc = (mz == 0) ? QSCALE : 1.0f;

    const int m0  = blockIdx.x * 128;
    const int h   = blockIdx.y;
    const int tid = threadIdx.x;
    const int w   = tid >> 6;
    const int l   = tid & 63;
    const int lr  = l & 15, lh = l >> 4;

    __shared__ u16 As[128][40];   // [m][k], +8 pad
    __shared__ u16 Bs[64][40];    // [n][k]  (B^T layout)

    f32x4 acc[2][4];
    const f32x4 fzero = {0.f, 0.f, 0.f, 0.f};
    #pragma unroll
    for (int i = 0; i < 2; ++i)
        #pragma unroll
        for (int j = 0; j < 4; ++j) acc[i][j] = fzero;

    for (int kt = 0; kt < 16; ++kt) {
        const int k0 = kt * 32;
        {
            const int row  = tid >> 1;
            const int part = (tid & 1) * 16;
            const float* src = x + (size_t)(m0 + row) * DMODEL + k0 + part;
            u16* dst = &As[row][part];
            #pragma unroll
            for (int q4 = 0; q4 < 4; ++q4) {
                float4 v = *(const float4*)(src + q4 * 4);
                dst[q4*4+0] = f2bf(v.x); dst[q4*4+1] = f2bf(v.y);
                dst[q4*4+2] = f2bf(v.z); dst[q4*4+3] = f2bf(v.w);
            }
        }
        #pragma unroll
        for (int rep = 0; rep < 2; ++rep) {
            const int idx = rep * 256 + tid;
            const int kk  = idx >> 4;
            const int n4  = (idx & 15) * 4;
            float4 v = *(const float4*)(W + (size_t)(k0 + kk) * DMODEL + h * 64 + n4);
            Bs[n4+0][kk] = f2bf(v.x);
            Bs[n4+1][kk] = f2bf(v.y);
            Bs[n4+2][kk] = f2bf(v.z);
            Bs[n4+3][kk] = f2bf(v.w);
        }
        __syncthreads();

        bf16x8 af[2];
        #pragma unroll
        for (int i = 0; i < 2; ++i)
            af[i] = *(const bf16x8*)&As[w*32 + i*16 + lr][lh*8];
        #pragma unroll
        for (int j = 0; j < 4; ++j) {
            bf16x8 bfB = *(const bf16x8*)&Bs[j*16 + lr][lh*8];
            #pragma unroll
            for (int i = 0; i < 2; ++i)
                acc[i][j] = __builtin_amdgcn_mfma_f32_16x16x32_bf16(af[i], bfB, acc[i][j], 0, 0, 0);
        }
        __syncthreads();
    }

    #pragma unroll
    for (int i = 0; i < 2; ++i) {
        #pragma unroll
        for (int j = 0; j < 4; ++j) {
            #pragma unroll
            for (int rr = 0; rr < 4; ++rr) {
                const int gm = m0 + w*32 + i*16 + lh*4 + rr;
                const int b  = gm >> 12;
                const int t  = gm & 4095;
                const int n  = t >> 2, r = t & 3;
                const int dk = j*16 + lr;
                const size_t gbase = (((size_t)(b*NH + h))*RATE + r);
                const size_t oidx = (mz == 2)
                    ? (gbase*DHEAD + dk)*NPAD + n       // V^T: [g][dv][n]
                    : (gbase*NPAD + n)*DHEAD + dk;      // Q,K: [g][n][dk]
                Ob[oidx] = f2bf(acc[i][j][rr] * osc);
            }
        }
    }
}

// ---------------------------------------------------------------------------
// Flash attention per (b,h,r) class: 64 queries/block, 17 key tiles of 64.
// No online max: p = exp2(s_log2); L accumulated per-lane, reduced once.
// ---------------------------------------------------------------------------
__global__ __launch_bounds__(256) void attn_kernel(
    const u16* __restrict__ Qb, const u16* __restrict__ Kb, const u16* __restrict__ Vb,
    float* __restrict__ out)
{
    const int g  = blockIdx.y;          // ((b*8+h)*4+r)
    const int b  = g >> 5;
    const int h  = (g >> 2) & 7;
    const int r  = g & 3;
    const int q0 = blockIdx.x * 64;
    const int tid = threadIdx.x;
    const int w  = tid >> 6;
    const int l  = tid & 63;
    const int lr = l & 15, lh = l >> 4;

    const u16* Qg  = Qb + (size_t)g * NPAD * DHEAD;
    const u16* Kg  = Kb + (size_t)g * NPAD * DHEAD;
    const u16* Vtg = Vb + (size_t)g * DHEAD * NPAD;   // [dv][n]

    __shared__ u16 Ks[64][72];       // [m][k], +8 pad
    __shared__ u16 Vs[64][72];       // [dv][m], +8 pad (staged from V^T, vectorized)
    __shared__ u16 Ps[4][16][68];    // per-wave P tile [qrow][m], stride 68 (conflict-free stores)

    // Q fragments, hoisted (wave w owns query rows q0+w*16 .. +15)
    bf16x8 qa[2];
    {
        const u16* qrow = Qg + (size_t)(q0 + w*16 + lr) * DHEAD;
        qa[0] = *(const bf16x8*)(qrow + lh*8);
        qa[1] = *(const bf16x8*)(qrow + 32 + lh*8);
    }

    const f32x4 fzero = {0.f, 0.f, 0.f, 0.f};
    f32x4 o[4];
    #pragma unroll
    for (int j = 0; j < 4; ++j) o[j] = fzero;
    float Lpart[4] = {0.f, 0.f, 0.f, 0.f};

    for (int mt = 0; mt < 17; ++mt) {
        const int m0 = mt * 64;
        // stage K tile and V^T tile (both fully vectorized b128 copies)
        #pragma unroll
        for (int rep = 0; rep < 2; ++rep) {
            const int cidx = rep * 256 + tid;    // 0..511
            const int row  = cidx >> 3;          // 0..63
            const int ch   = cidx & 7;           // 16B chunk
            *(bf16x8*)&Ks[row][ch*8] =
                *(const bf16x8*)(Kg + (size_t)(m0 + row) * DHEAD + ch*8);
            *(bf16x8*)&Vs[row][ch*8] =
                *(const bf16x8*)(Vtg + (size_t)row * NPAD + m0 + ch*8);
        }
        __syncthreads();

        // S = Q K^T  (wave: 16 x 64), logits already in log2 space
        f32x4 s[4];
        #pragma unroll
        for (int ni = 0; ni < 4; ++ni) {
            s[ni] = fzero;
            #pragma unroll
            for (int kk = 0; kk < 2; ++kk) {
                bf16x8 kb = *(const bf16x8*)&Ks[ni*16 + lr][kk*32 + lh*8];
                s[ni] = __builtin_amdgcn_mfma_f32_16x16x32_bf16(qa[kk], kb, s[ni], 0, 0, 0);
            }
        }

        // softmax numerator terms (fixed M=0): p = exp2(s) [+1 in band, 0 if key masked]
        const bool special = (m0 + 66 >= q0) && (m0 <= q0 + 66);
        if (!special && mt != 16) {
            #pragma unroll
            for (int ni = 0; ni < 4; ++ni) {
                #pragma unroll
                for (int rr = 0; rr < 4; ++rr) {
                    const float p = __builtin_amdgcn_exp2f(s[ni][rr]);
                    Lpart[rr] += p;
                    Ps[w][lh*4 + rr][ni*16 + lr] = f2bf(p);
                }
            }
        } else {
            #pragma unroll
            for (int ni = 0; ni < 4; ++ni) {
                const int mg = m0 + ni*16 + lr;
                #pragma unroll
                for (int rr = 0; rr < 4; ++rr) {
                    const int qg = q0 + w*16 + lh*4 + rr;
                    float v = s[ni][rr];
                    const int dd = mg - qg;
                    if (mg > 1024)                 v = -1e30f;     // exp2 -> 0
                    else if (dd >= -3 && dd <= 3)  v += 1.0f;      // window double (ln2 in log2 space)
                    const float p = __builtin_amdgcn_exp2f(v);
                    Lpart[rr] += p;
                    Ps[w][lh*4 + rr][ni*16 + lr] = f2bf(p);
                }
            }
        }

        // O += P V   (Ps is per-wave: intra-wave lgkmcnt dependency only)
        #pragma unroll
        for (int kk = 0; kk < 2; ++kk) {
            bf16x8 pa = *(const bf16x8*)&Ps[w][lr][kk*32 + lh*8];
            #pragma unroll
            for (int j = 0; j < 4; ++j) {
                bf16x8 vb = *(const bf16x8*)&Vs[j*16 + lr][kk*32 + lh*8];
                o[j] = __builtin_amdgcn_mfma_f32_16x16x32_bf16(pa, vb, o[j], 0, 0, 0);
            }
        }
        __syncthreads();
    }

    // epilogue: reduce L across the 16-lane row groups; OOB window slots add
    // coob * exp2(0 - 0) = coob to the denominator.
    #pragma unroll
    for (int rr = 0; rr < 4; ++rr) {
        float s_ = Lpart[rr];
        #pragma unroll
        for (int off = 1; off < 16; off <<= 1)
            s_ += __shfl_xor(s_, off, 16);
        const int qg = q0 + w*16 + lh*4 + rr;
        const int coob = (qg < 3 ? 3 - qg : 0) + (qg > 1021 ? qg - 1021 : 0);
        const float inv = 1.0f / (s_ + (float)coob);
        const int t = qg * 4 + r;
        float* orow = out + ((size_t)b * LSEQ + t) * DMODEL + h * DHEAD;
        #pragma unroll
        for (int j = 0; j < 4; ++j)
            orow[j*16 + lr] = o[j][rr] * inv;
    }
}

extern "C" void kernel_launch(void* const* d_in, const int* in_sizes, int n_in,
                              void* d_out, int out_size, void* d_ws, size_t ws_size,
                              hipStream_t stream) {
    const float* x  = (const float*)d_in[0];
    const float* Wq = (const float*)d_in[1];
    const float* Wk = (const float*)d_in[2];
    const float* Wv = (const float*)d_in[3];
    float* out = (float*)d_out;

    const size_t SZ = (size_t)BATCH * NH * RATE * NPAD * DHEAD;  // elems per tensor
    u16* Qb = (u16*)d_ws;
    u16* Kb = Qb + SZ;
    u16* Vb = Kb + SZ;

    // zero-fill gives the pad rows (n >= 1024) their required zeros
    hipMemsetAsync(d_ws, 0, 3 * SZ * sizeof(u16), stream);

    dim3 gp(64, 8, 3);                 // 8192/128 M-tiles, 8 heads, q/k/v
    proj_kernel<<<gp, 256, 0, stream>>>(x, Wq, Wk, Wv, Qb, Kb, Vb);

    dim3 ga(16, 64);                   // 16 query tiles, 64 (b,h,r) groups
    attn_kernel<<<ga, 256, 0, stream>>>(Qb, Kb, Vb, out);
}

// Round 3
// 81.650 us; speedup vs baseline: 1.8844x; 1.4175x over previous
//
#include <hip/hip_runtime.h>
#include <hip/hip_bf16.h>

// Sparse self-attention == dense attention within each residue class (mod 4)
// + 7-wide window (duplicate entries => logit += ln2, i.e. +1.0 in log2 space)
// + OOB window slots adding exp(0) to the denominator.
// Pipeline: prep (fp32->bf16 x, transpose W) -> fused QKV GEMM (MFMA,
// global_load_lds, V written transposed via LDS retile) -> flash attention.

#define BATCH 2
#define LSEQ  4096
#define DMODEL 512
#define NH    8
#define DHEAD 64
#define NPAD  1088      // key rows padded to 17*64 (valid: 0..1024; m=1024 = zero key)
#define NQ    1024
#define QSCALE 0.18033688011112042f   // 0.125 * log2(e)

typedef __bf16 bf16x8 __attribute__((ext_vector_type(8)));
typedef __attribute__((ext_vector_type(4))) float f32x4;
typedef unsigned short u16;
typedef unsigned int u32;
typedef __attribute__((ext_vector_type(8))) u16 u16x8;
typedef __attribute__((ext_vector_type(4))) u16 u16x4;

__device__ __forceinline__ u16 f2bf(float f) {
    u32 u = __float_as_uint(f);
    u += 0x7fffu + ((u >> 16) & 1u);   // RNE, finite inputs
    return (u16)(u >> 16);
}

__device__ __forceinline__ void gload16(const u16* g, u16* l) {
    __builtin_amdgcn_global_load_lds(
        (const __attribute__((address_space(1))) u32*)(const void*)g,
        (__attribute__((address_space(3))) u32*)(void*)l, 16, 0, 0);
}

// ---------------------------------------------------------------------------
// prep: xb[t][k] = bf16(x[t][k]);  Wt[c][k] = bf16(W_mat[k][col]) (transposed)
// c = mat*512 + col.  Blocks 0..2047: x convert; 2048..2239: W transpose.
// ---------------------------------------------------------------------------
__global__ __launch_bounds__(256) void prep_kernel(
    const float* __restrict__ x,
    const float* __restrict__ Wq, const float* __restrict__ Wk, const float* __restrict__ Wv,
    u16* __restrict__ xb, u16* __restrict__ Wt)
{
    const int bid = blockIdx.x, tid = threadIdx.x;
    if (bid < 2048) {
        const size_t i0 = (size_t)bid * 2048 + (size_t)tid * 8;
        float4 a = *(const float4*)(x + i0);
        float4 b = *(const float4*)(x + i0 + 4);
        u16x8 o = { f2bf(a.x), f2bf(a.y), f2bf(a.z), f2bf(a.w),
                    f2bf(b.x), f2bf(b.y), f2bf(b.z), f2bf(b.w) };
        *(u16x8*)(xb + i0) = o;
    } else {
        const int wb  = bid - 2048;            // 0..191
        const int mat = wb >> 6;
        const int t   = wb & 63;
        const int k0  = (t >> 3) * 64, c0 = (t & 7) * 64;
        const float* W = (mat == 0) ? Wq : (mat == 1) ? Wk : Wv;
        __shared__ u16 Ws[64][72];             // [k][c]
        #pragma unroll
        for (int i = 0; i < 4; ++i) {
            const int chunk = i * 256 + tid;
            const int kr = chunk >> 4, c4 = (chunk & 15) * 4;
            float4 v = *(const float4*)(W + (size_t)(k0 + kr) * DMODEL + c0 + c4);
            u16x4 q = { f2bf(v.x), f2bf(v.y), f2bf(v.z), f2bf(v.w) };
            *(u16x4*)&Ws[kr][c4] = q;
        }
        __syncthreads();
        const int cc = tid >> 2, kq = (tid & 3) * 16;
        alignas(16) u16 tmp[16];
        #pragma unroll
        for (int kk = 0; kk < 16; ++kk) tmp[kk] = Ws[kq + kk][cc];
        u16* dst = Wt + (size_t)(mat * 512 + c0 + cc) * DMODEL + k0 + kq;
        *(u16x8*)dst       = *(const u16x8*)&tmp[0];
        *(u16x8*)(dst + 8) = *(const u16x8*)&tmp[8];
    }
}

// ---------------------------------------------------------------------------
// Fused QKV GEMM: C = xb(8192x512) * Wt^T(512x1536), bf16 MFMA, BM=BN=128,
// BK=64, 4 waves (2x2), global_load_lds staging with XOR-swizzled source.
// nt 0-3 -> Q (scaled), 4-7 -> K, 8-11 -> V (written transposed via LDS).
// ---------------------------------------------------------------------------
__global__ __launch_bounds__(256) void gemm_kernel(
    const u16* __restrict__ xb, const u16* __restrict__ Wt,
    u16* __restrict__ Qb, u16* __restrict__ Kb, u16* __restrict__ Vb)
{
    const int m0 = blockIdx.x * 128;
    const int nt = blockIdx.y;
    const int n0 = nt * 128;
    const int tid = threadIdx.x;
    const int w = tid >> 6, l = tid & 63, lr = l & 15, lh = l >> 4;
    const int wr = w >> 1, wc = w & 1;

    __shared__ u16 smem[16896];     // A:[0,8192) B:[8192,16384); V-retile 128*132
    u16* As = smem;
    u16* Bs = smem + 8192;

    f32x4 acc[4][4];
    const f32x4 fzero = {0.f, 0.f, 0.f, 0.f};
    #pragma unroll
    for (int mi = 0; mi < 4; ++mi)
        #pragma unroll
        for (int nj = 0; nj < 4; ++nj) acc[mi][nj] = fzero;

    for (int kt = 0; kt < 8; ++kt) {
        const int k0 = kt * 64;
        // stage A,B: 4 insts each, 16B/lane; source chunk XOR-swizzled so the
        // (linear-dest) LDS ends with A[row][ (ch^(row&7))*8 ] layout.
        #pragma unroll
        for (int i = 0; i < 4; ++i) {
            const int cid = i * 256 + tid;
            const int row = cid >> 3, ch = cid & 7;
            const int sch = ch ^ (row & 7);
            u16* dstA = As + (i * 256 + w * 64) * 8;   // wave-uniform base
            u16* dstB = Bs + (i * 256 + w * 64) * 8;
            gload16(xb + (size_t)(m0 + row) * DMODEL + k0 + sch * 8, dstA);
            gload16(Wt + (size_t)(n0 + row) * DMODEL + k0 + sch * 8, dstB);
        }
        __syncthreads();

        #pragma unroll
        for (int kk = 0; kk < 2; ++kk) {
            const int cs = (kk * 4 + lh) ^ (lr & 7);   // swizzled chunk
            bf16x8 af[4], bfr[4];
            #pragma unroll
            for (int mi = 0; mi < 4; ++mi)
                af[mi] = *(const bf16x8*)(As + (wr * 64 + mi * 16 + lr) * 64 + cs * 8);
            #pragma unroll
            for (int nj = 0; nj < 4; ++nj)
                bfr[nj] = *(const bf16x8*)(Bs + (wc * 64 + nj * 16 + lr) * 64 + cs * 8);
            #pragma unroll
            for (int mi = 0; mi < 4; ++mi)
                #pragma unroll
                for (int nj = 0; nj < 4; ++nj)
                    acc[mi][nj] = __builtin_amdgcn_mfma_f32_16x16x32_bf16(af[mi], bfr[nj], acc[mi][nj], 0, 0, 0);
        }
        __syncthreads();
    }

    const int mat = nt >> 2;
    const int hp  = nt & 3;
    if (mat < 2) {
        u16* Ob = (mat == 0) ? Qb : Kb;
        const float osc = (mat == 0) ? QSCALE : 1.0f;
        #pragma unroll
        for (int mi = 0; mi < 4; ++mi) {
            const int gmb = m0 + wr * 64 + mi * 16 + lh * 4;
            const int b = gmb >> 12;
            #pragma unroll
            for (int rr = 0; rr < 4; ++rr) {
                const int t = (gmb + rr) & 4095;
                const int n = t >> 2, r = t & 3;
                #pragma unroll
                for (int nj = 0; nj < 4; ++nj) {
                    const int c  = wc * 64 + nj * 16 + lr;
                    const int h  = hp * 2 + (c >> 6);
                    const int dk = c & 63;
                    const size_t g = ((size_t)(b * NH + h)) * 4 + r;
                    Ob[(g * NPAD + n) * DHEAD + dk] = f2bf(acc[mi][nj][rr] * osc);
                }
            }
        }
    } else {
        // V: retile via LDS -> coalesced 64B-line stores of V^T [g][dv][n]
        #pragma unroll
        for (int mi = 0; mi < 4; ++mi) {
            const int nrel = wr * 16 + mi * 4 + lh;
            #pragma unroll
            for (int nj = 0; nj < 4; ++nj) {
                const int c = wc * 64 + nj * 16 + lr;
                #pragma unroll
                for (int rr = 0; rr < 4; ++rr)
                    smem[c * 132 + rr * 32 + nrel] = f2bf(acc[mi][nj][rr]);
            }
        }
        __syncthreads();
        const int b  = m0 >> 12;
        const int nb = (m0 & 4095) >> 2;     // base class-row, 32-aligned
        #pragma unroll
        for (int e = 0; e < 2; ++e) {
            const int chunk = e * 256 + tid;        // 0..511
            const int c = chunk & 127, r = chunk >> 7;
            const int h  = hp * 2 + (c >> 6);
            const int dv = c & 63;
            const size_t g = ((size_t)(b * NH + h)) * 4 + r;
            u16* dst = Vb + (g * DHEAD + dv) * NPAD + nb;
            const u16* src = smem + c * 132 + r * 32;
            alignas(16) u16 tmp[32];
            #pragma unroll
            for (int q8 = 0; q8 < 8; ++q8)
                *(u16x4*)&tmp[q8 * 4] = *(const u16x4*)(src + q8 * 4);
            #pragma unroll
            for (int q16 = 0; q16 < 4; ++q16)
                *(u16x8*)(dst + q16 * 8) = *(const u16x8*)&tmp[q16 * 8];
        }
    }
}

// ---------------------------------------------------------------------------
// Flash attention per (b,h,r): 128 queries/block (8 waves), 17 key tiles of 64.
// Log2-space logits (scale baked into Q); no online max; per-lane L partials.
// ---------------------------------------------------------------------------
__global__ __launch_bounds__(512) void attn_kernel(
    const u16* __restrict__ Qb, const u16* __restrict__ Kb, const u16* __restrict__ Vb,
    float* __restrict__ out)
{
    const int g  = blockIdx.y;          // ((b*8+h)*4+r)
    const int b  = g >> 5;
    const int h  = (g >> 2) & 7;
    const int r  = g & 3;
    const int q0 = blockIdx.x * 128;
    const int tid = threadIdx.x;
    const int w  = tid >> 6;            // 0..7
    const int l  = tid & 63;
    const int lr = l & 15, lh = l >> 4;

    const u16* Qg  = Qb + (size_t)g * NPAD * DHEAD;
    const u16* Kg  = Kb + (size_t)g * NPAD * DHEAD;
    const u16* Vtg = Vb + (size_t)g * DHEAD * NPAD;   // [dv][n]

    __shared__ u16 Ks[64][72];
    __shared__ u16 Vs[64][72];
    __shared__ u16 Ps[8][16][68];

    bf16x8 qa[2];
    {
        const u16* qrow = Qg + (size_t)(q0 + w * 16 + lr) * DHEAD;
        qa[0] = *(const bf16x8*)(qrow + lh * 8);
        qa[1] = *(const bf16x8*)(qrow + 32 + lh * 8);
    }

    const f32x4 fzero = {0.f, 0.f, 0.f, 0.f};
    f32x4 o[4];
    #pragma unroll
    for (int j = 0; j < 4; ++j) o[j] = fzero;
    float Lpart[4] = {0.f, 0.f, 0.f, 0.f};

    const int qw0 = q0 + w * 16;

    for (int mt = 0; mt < 17; ++mt) {
        const int m0 = mt * 64;
        {
            const int row = tid >> 3, ch = tid & 7;
            *(bf16x8*)&Ks[row][ch * 8] =
                *(const bf16x8*)(Kg + (size_t)(m0 + row) * DHEAD + ch * 8);
            *(bf16x8*)&Vs[row][ch * 8] =
                *(const bf16x8*)(Vtg + (size_t)row * NPAD + m0 + ch * 8);
        }
        __syncthreads();

        f32x4 s[4];
        #pragma unroll
        for (int ni = 0; ni < 4; ++ni) {
            s[ni] = fzero;
            #pragma unroll
            for (int kk = 0; kk < 2; ++kk) {
                bf16x8 kb = *(const bf16x8*)&Ks[ni * 16 + lr][kk * 32 + lh * 8];
                s[ni] = __builtin_amdgcn_mfma_f32_16x16x32_bf16(qa[kk], kb, s[ni], 0, 0, 0);
            }
        }

        const bool special = (mt == 16) || ((m0 + 66 >= qw0) && (m0 <= qw0 + 18));
        if (!special) {
            #pragma unroll
            for (int ni = 0; ni < 4; ++ni) {
                #pragma unroll
                for (int rr = 0; rr < 4; ++rr) {
                    const float p = __builtin_amdgcn_exp2f(s[ni][rr]);
                    Lpart[rr] += p;
                    Ps[w][lh * 4 + rr][ni * 16 + lr] = f2bf(p);
                }
            }
        } else {
            #pragma unroll
            for (int ni = 0; ni < 4; ++ni) {
                const int mg = m0 + ni * 16 + lr;
                #pragma unroll
                for (int rr = 0; rr < 4; ++rr) {
                    const int qg = qw0 + lh * 4 + rr;
                    float v = s[ni][rr];
                    const int dd = mg - qg;
                    if (mg > 1024)                 v = -1e30f;   // exp2 -> 0
                    else if (dd >= -3 && dd <= 3)  v += 1.0f;    // window doubling
                    const float p = __builtin_amdgcn_exp2f(v);
                    Lpart[rr] += p;
                    Ps[w][lh * 4 + rr][ni * 16 + lr] = f2bf(p);
                }
            }
        }

        #pragma unroll
        for (int kk = 0; kk < 2; ++kk) {
            bf16x8 pa = *(const bf16x8*)&Ps[w][lr][kk * 32 + lh * 8];
            #pragma unroll
            for (int j = 0; j < 4; ++j) {
                bf16x8 vb = *(const bf16x8*)&Vs[j * 16 + lr][kk * 32 + lh * 8];
                o[j] = __builtin_amdgcn_mfma_f32_16x16x32_bf16(pa, vb, o[j], 0, 0, 0);
            }
        }
        __syncthreads();
    }

    #pragma unroll
    for (int rr = 0; rr < 4; ++rr) {
        float s_ = Lpart[rr];
        #pragma unroll
        for (int off = 1; off < 16; off <<= 1)
            s_ += __shfl_xor(s_, off, 16);
        const int qg = qw0 + lh * 4 + rr;
        const int coob = (qg < 3 ? 3 - qg : 0) + (qg > 1021 ? qg - 1021 : 0);
        const float inv = 1.0f / (s_ + (float)coob);
        const int t = qg * 4 + r;
        float* orow = out + ((size_t)b * LSEQ + t) * DMODEL + h * DHEAD;
        #pragma unroll
        for (int j = 0; j < 4; ++j)
            orow[j * 16 + lr] = o[j][rr] * inv;
    }
}

extern "C" void kernel_launch(void* const* d_in, const int* in_sizes, int n_in,
                              void* d_out, int out_size, void* d_ws, size_t ws_size,
                              hipStream_t stream) {
    const float* x  = (const float*)d_in[0];
    const float* Wq = (const float*)d_in[1];
    const float* Wk = (const float*)d_in[2];
    const float* Wv = (const float*)d_in[3];
    float* out = (float*)d_out;

    const size_t SZ = (size_t)BATCH * NH * 4 * NPAD * DHEAD;   // per-tensor elems
    u16* Qb = (u16*)d_ws;
    u16* Kb = Qb + SZ;
    u16* Vb = Kb + SZ;

    // scratch for bf16 x and transposed W lives in d_out (overwritten by attn)
    u16* xb = (u16*)d_out;                       // 8192*512 u16
    u16* Wt = xb + (size_t)8192 * 512;           // 1536*512 u16

    // K tail rows (n>=1024, incl. the zero key n=1024) and V^T tails must be 0
    hipMemsetAsync(Kb, 0, 2 * SZ * sizeof(u16), stream);

    prep_kernel<<<2240, 256, 0, stream>>>(x, Wq, Wk, Wv, xb, Wt);

    dim3 gg(64, 12);
    gemm_kernel<<<gg, 256, 0, stream>>>(xb, Wt, Qb, Kb, Vb);

    dim3 ga(8, 64);
    attn_kernel<<<ga, 512, 0, stream>>>(Qb, Kb, Vb, out);
}

// Round 4
// 67.912 us; speedup vs baseline: 2.2657x; 1.2023x over previous
//
#include <hip/hip_runtime.h>
#include <hip/hip_bf16.h>

// Sparse self-attention == dense attention within each residue class (mod 4)
// + 7-wide window (duplicate entries => logit += 1.0 in log2 space)
// + OOB window slots adding exp(0)=1 to the denominator.
// prep (x->bf16, W transpose, K/V tail zero) -> fused QKV GEMM -> flash attn
// (async gload_lds staging, double-buffered, XCD-local grid).

#define BATCH 2
#define LSEQ  4096
#define DMODEL 512
#define NH    8
#define DHEAD 64
#define NPAD  1088      // key rows padded to 17*64 (valid: 0..1024; n=1024 = zero key)
#define QSCALE 0.18033688011112042f   // 0.125 * log2(e)

typedef __bf16 bf16x8 __attribute__((ext_vector_type(8)));
typedef __attribute__((ext_vector_type(4))) float f32x4;
typedef unsigned short u16;
typedef unsigned int u32;
typedef __attribute__((ext_vector_type(8))) u16 u16x8;
typedef __attribute__((ext_vector_type(4))) u16 u16x4;

__device__ __forceinline__ u16 f2bf(float f) {
    u32 u = __float_as_uint(f);
    u += 0x7fffu + ((u >> 16) & 1u);   // RNE, finite inputs
    return (u16)(u >> 16);
}

__device__ __forceinline__ void gload16(const u16* g, u16* l) {
    __builtin_amdgcn_global_load_lds(
        (const __attribute__((address_space(1))) u32*)(const void*)g,
        (__attribute__((address_space(3))) u32*)(void*)l, 16, 0, 0);
}

// ---------------------------------------------------------------------------
// prep: bid<2048: xb = bf16(x);  2048..2239: Wt[c][k] = bf16(W[k][c]) transposed;
//       2240..2303: zero K tail rows and V^T tail cols for g = bid-2240.
// ---------------------------------------------------------------------------
__global__ __launch_bounds__(256) void prep_kernel(
    const float* __restrict__ x,
    const float* __restrict__ Wq, const float* __restrict__ Wk, const float* __restrict__ Wv,
    u16* __restrict__ xb, u16* __restrict__ Wt,
    u16* __restrict__ Kb, u16* __restrict__ Vb)
{
    const int bid = blockIdx.x, tid = threadIdx.x;
    if (bid < 2048) {
        const size_t i0 = (size_t)bid * 2048 + (size_t)tid * 8;
        float4 a = *(const float4*)(x + i0);
        float4 b = *(const float4*)(x + i0 + 4);
        u16x8 o = { f2bf(a.x), f2bf(a.y), f2bf(a.z), f2bf(a.w),
                    f2bf(b.x), f2bf(b.y), f2bf(b.z), f2bf(b.w) };
        *(u16x8*)(xb + i0) = o;
    } else if (bid < 2240) {
        const int wb  = bid - 2048;            // 0..191
        const int mat = wb >> 6;
        const int t   = wb & 63;
        const int k0  = (t >> 3) * 64, c0 = (t & 7) * 64;
        const float* W = (mat == 0) ? Wq : (mat == 1) ? Wk : Wv;
        __shared__ u16 Ws[64][72];             // [k][c]
        #pragma unroll
        for (int i = 0; i < 4; ++i) {
            const int chunk = i * 256 + tid;
            const int kr = chunk >> 4, c4 = (chunk & 15) * 4;
            float4 v = *(const float4*)(W + (size_t)(k0 + kr) * DMODEL + c0 + c4);
            u16x4 q = { f2bf(v.x), f2bf(v.y), f2bf(v.z), f2bf(v.w) };
            *(u16x4*)&Ws[kr][c4] = q;
        }
        __syncthreads();
        const int cc = tid >> 2, kq = (tid & 3) * 16;
        alignas(16) u16 tmp[16];
        #pragma unroll
        for (int kk = 0; kk < 16; ++kk) tmp[kk] = Ws[kq + kk][cc];
        u16* dst = Wt + (size_t)(mat * 512 + c0 + cc) * DMODEL + k0 + kq;
        *(u16x8*)dst       = *(const u16x8*)&tmp[0];
        *(u16x8*)(dst + 8) = *(const u16x8*)&tmp[8];
    } else {
        const int g = bid - 2240;              // 0..63
        const u16x8 z = {0,0,0,0,0,0,0,0};
        // K tail: rows 1024..1087 (4096 u16 contiguous): 256 thr x 16 u16
        u16* kt = Kb + ((size_t)g * NPAD + 1024) * DHEAD + tid * 16;
        *(u16x8*)kt       = z;
        *(u16x8*)(kt + 8) = z;
        // V^T tail: for each dv row, cols 1024..1087: thr -> (dv=tid>>2, 16 cols)
        u16* vt = Vb + ((size_t)g * DHEAD + (tid >> 2)) * NPAD + 1024 + (tid & 3) * 16;
        *(u16x8*)vt       = z;
        *(u16x8*)(vt + 8) = z;
    }
}

// ---------------------------------------------------------------------------
// Fused QKV GEMM: C = xb(8192x512) * Wt^T(512x1536), BM=BN=128, BK=64, 4 waves.
// nt 0-3 -> Q (scaled), 4-7 -> K, 8-11 -> V (written transposed via LDS retile).
// ---------------------------------------------------------------------------
__global__ __launch_bounds__(256) void gemm_kernel(
    const u16* __restrict__ xb, const u16* __restrict__ Wt,
    u16* __restrict__ Qb, u16* __restrict__ Kb, u16* __restrict__ Vb)
{
    const int m0 = blockIdx.x * 128;
    const int nt = blockIdx.y;
    const int n0 = nt * 128;
    const int tid = threadIdx.x;
    const int w = tid >> 6, l = tid & 63, lr = l & 15, lh = l >> 4;
    const int wr = w >> 1, wc = w & 1;

    __shared__ u16 smem[16896];     // A:[0,8192) B:[8192,16384); V-retile 128*132
    u16* As = smem;
    u16* Bs = smem + 8192;

    f32x4 acc[4][4];
    const f32x4 fzero = {0.f, 0.f, 0.f, 0.f};
    #pragma unroll
    for (int mi = 0; mi < 4; ++mi)
        #pragma unroll
        for (int nj = 0; nj < 4; ++nj) acc[mi][nj] = fzero;

    for (int kt = 0; kt < 8; ++kt) {
        const int k0 = kt * 64;
        #pragma unroll
        for (int i = 0; i < 4; ++i) {
            const int cid = i * 256 + tid;
            const int row = cid >> 3, ch = cid & 7;
            const int sch = ch ^ (row & 7);
            u16* dstA = As + (i * 256 + w * 64) * 8;   // wave-uniform base
            u16* dstB = Bs + (i * 256 + w * 64) * 8;
            gload16(xb + (size_t)(m0 + row) * DMODEL + k0 + sch * 8, dstA);
            gload16(Wt + (size_t)(n0 + row) * DMODEL + k0 + sch * 8, dstB);
        }
        __syncthreads();

        #pragma unroll
        for (int kk = 0; kk < 2; ++kk) {
            const int cs = (kk * 4 + lh) ^ (lr & 7);   // swizzled chunk
            bf16x8 af[4], bfr[4];
            #pragma unroll
            for (int mi = 0; mi < 4; ++mi)
                af[mi] = *(const bf16x8*)(As + (wr * 64 + mi * 16 + lr) * 64 + cs * 8);
            #pragma unroll
            for (int nj = 0; nj < 4; ++nj)
                bfr[nj] = *(const bf16x8*)(Bs + (wc * 64 + nj * 16 + lr) * 64 + cs * 8);
            #pragma unroll
            for (int mi = 0; mi < 4; ++mi)
                #pragma unroll
                for (int nj = 0; nj < 4; ++nj)
                    acc[mi][nj] = __builtin_amdgcn_mfma_f32_16x16x32_bf16(af[mi], bfr[nj], acc[mi][nj], 0, 0, 0);
        }
        __syncthreads();
    }

    const int mat = nt >> 2;
    const int hp  = nt & 3;
    if (mat < 2) {
        u16* Ob = (mat == 0) ? Qb : Kb;
        const float osc = (mat == 0) ? QSCALE : 1.0f;
        #pragma unroll
        for (int mi = 0; mi < 4; ++mi) {
            const int gmb = m0 + wr * 64 + mi * 16 + lh * 4;
            const int b = gmb >> 12;
            #pragma unroll
            for (int rr = 0; rr < 4; ++rr) {
                const int t = (gmb + rr) & 4095;
                const int n = t >> 2, r = t & 3;
                #pragma unroll
                for (int nj = 0; nj < 4; ++nj) {
                    const int c  = wc * 64 + nj * 16 + lr;
                    const int h  = hp * 2 + (c >> 6);
                    const int dk = c & 63;
                    const size_t g = ((size_t)(b * NH + h)) * 4 + r;
                    Ob[(g * NPAD + n) * DHEAD + dk] = f2bf(acc[mi][nj][rr] * osc);
                }
            }
        }
    } else {
        // V: retile via LDS -> coalesced stores of V^T [g][dv][n]
        #pragma unroll
        for (int mi = 0; mi < 4; ++mi) {
            const int nrel = wr * 16 + mi * 4 + lh;
            #pragma unroll
            for (int nj = 0; nj < 4; ++nj) {
                const int c = wc * 64 + nj * 16 + lr;
                #pragma unroll
                for (int rr = 0; rr < 4; ++rr)
                    smem[c * 132 + rr * 32 + nrel] = f2bf(acc[mi][nj][rr]);
            }
        }
        __syncthreads();
        const int b  = m0 >> 12;
        const int nb = (m0 & 4095) >> 2;
        #pragma unroll
        for (int e = 0; e < 2; ++e) {
            const int chunk = e * 256 + tid;
            const int c = chunk & 127, r = chunk >> 7;
            const int h  = hp * 2 + (c >> 6);
            const int dv = c & 63;
            const size_t g = ((size_t)(b * NH + h)) * 4 + r;
            u16* dst = Vb + (g * DHEAD + dv) * NPAD + nb;
            const u16* src = smem + c * 132 + r * 32;
            alignas(16) u16 tmp[32];
            #pragma unroll
            for (int q8 = 0; q8 < 8; ++q8)
                *(u16x4*)&tmp[q8 * 4] = *(const u16x4*)(src + q8 * 4);
            #pragma unroll
            for (int q16 = 0; q16 < 4; ++q16)
                *(u16x8*)(dst + q16 * 8) = *(const u16x8*)&tmp[q16 * 8];
        }
    }
}

// ---------------------------------------------------------------------------
// Flash attention per (b,h,r): 128 queries/block (8 waves), 17 key tiles of 64.
// K/V staged via global_load_lds (XOR-swizzled source, linear dest), double-
// buffered with counted vmcnt(2). Grid: x = g (XCD-local), y = q-block.
// ---------------------------------------------------------------------------
__global__ __launch_bounds__(512) void attn_kernel(
    const u16* __restrict__ Qb, const u16* __restrict__ Kb, const u16* __restrict__ Vb,
    float* __restrict__ out)
{
    const int g  = blockIdx.x;          // ((b*8+h)*4+r): blocks sharing g -> same XCD
    const int b  = g >> 5;
    const int h  = (g >> 2) & 7;
    const int r  = g & 3;
    const int q0 = blockIdx.y * 128;
    const int tid = threadIdx.x;
    const int w  = tid >> 6;            // 0..7
    const int l  = tid & 63;
    const int lr = l & 15, lh = l >> 4;

    const u16* Qg  = Qb + (size_t)g * NPAD * DHEAD;
    const u16* Kg  = Kb + (size_t)g * NPAD * DHEAD;
    const u16* Vtg = Vb + (size_t)g * DHEAD * NPAD;   // [dv][n]

    __shared__ u16 KV[2][2][4096];   // [buf][K/V][64 rows][8 slots][8 u16]
    __shared__ u16 Ps[8][16][68];

    // staging addresses: thread -> (row = tid>>3, slot = tid&7), source chunk
    // XOR-swizzled so LDS slot s of row holds chunk s^(row&7).
    const int srow = tid >> 3;
    const int ssch = (tid & 7) ^ (srow & 7);
    const u16* ksrc0 = Kg  + (size_t)srow * DHEAD + ssch * 8;
    const u16* vsrc0 = Vtg + (size_t)srow * NPAD  + ssch * 8;

    bf16x8 qa[2];
    {
        const u16* qrow = Qg + (size_t)(q0 + w * 16 + lr) * DHEAD;
        qa[0] = *(const bf16x8*)(qrow + lh * 8);
        qa[1] = *(const bf16x8*)(qrow + 32 + lh * 8);
    }

    const f32x4 fzero = {0.f, 0.f, 0.f, 0.f};
    f32x4 o[4];
    #pragma unroll
    for (int j = 0; j < 4; ++j) o[j] = fzero;
    float Lpart[4] = {0.f, 0.f, 0.f, 0.f};

    const int qw0 = q0 + w * 16;

    // prologue: stage tile 0 into buf 0
    gload16(ksrc0, &KV[0][0][w * 512]);
    gload16(vsrc0 + 0, &KV[0][1][w * 512]);

    int cur = 0;
    for (int mt = 0; mt < 17; ++mt) {
        if (mt < 16) {
            // issue next tile into the other buffer, then wait for current
            gload16(ksrc0 + (size_t)(mt + 1) * 4096, &KV[cur ^ 1][0][w * 512]);
            gload16(vsrc0 + (mt + 1) * 64,           &KV[cur ^ 1][1][w * 512]);
            asm volatile("s_waitcnt vmcnt(2)" ::: "memory");
        } else {
            asm volatile("s_waitcnt vmcnt(0)" ::: "memory");
        }
        __builtin_amdgcn_s_barrier();

        const u16* Kbuf = KV[cur][0];
        const u16* Vbuf = KV[cur][1];

        // S = Q K^T (wave: 16 x 64), logits already in log2 space
        f32x4 s[4];
        #pragma unroll
        for (int ni = 0; ni < 4; ++ni) {
            s[ni] = fzero;
            #pragma unroll
            for (int kk = 0; kk < 2; ++kk) {
                const int slot = (kk * 4 + lh) ^ (lr & 7);
                bf16x8 kb = *(const bf16x8*)(Kbuf + ((ni * 16 + lr) * 8 + slot) * 8);
                s[ni] = __builtin_amdgcn_mfma_f32_16x16x32_bf16(qa[kk], kb, s[ni], 0, 0, 0);
            }
        }

        const int m0 = mt * 64;
        const bool special = (mt == 16) || ((m0 + 66 >= qw0) && (m0 <= qw0 + 18));
        if (!special) {
            #pragma unroll
            for (int ni = 0; ni < 4; ++ni) {
                #pragma unroll
                for (int rr = 0; rr < 4; ++rr) {
                    const float p = __builtin_amdgcn_exp2f(s[ni][rr]);
                    Lpart[rr] += p;
                    Ps[w][lh * 4 + rr][ni * 16 + lr] = f2bf(p);
                }
            }
        } else {
            #pragma unroll
            for (int ni = 0; ni < 4; ++ni) {
                const int mg = m0 + ni * 16 + lr;
                #pragma unroll
                for (int rr = 0; rr < 4; ++rr) {
                    const int qg = qw0 + lh * 4 + rr;
                    float v = s[ni][rr];
                    const int dd = mg - qg;
                    if (mg > 1024)                 v = -1e30f;   // exp2 -> 0
                    else if (dd >= -3 && dd <= 3)  v += 1.0f;    // window doubling
                    const float p = __builtin_amdgcn_exp2f(v);
                    Lpart[rr] += p;
                    Ps[w][lh * 4 + rr][ni * 16 + lr] = f2bf(p);
                }
            }
        }

        // O += P V (Ps per-wave; Vbuf swizzled slots)
        #pragma unroll
        for (int kk = 0; kk < 2; ++kk) {
            bf16x8 pa = *(const bf16x8*)&Ps[w][lr][kk * 32 + lh * 8];
            #pragma unroll
            for (int j = 0; j < 4; ++j) {
                const int slot = (kk * 4 + lh) ^ (lr & 7);
                bf16x8 vb = *(const bf16x8*)(Vbuf + ((j * 16 + lr) * 8 + slot) * 8);
                o[j] = __builtin_amdgcn_mfma_f32_16x16x32_bf16(pa, vb, o[j], 0, 0, 0);
            }
        }
        __syncthreads();   // all waves done reading buf before next-iter writes
        cur ^= 1;
    }

    #pragma unroll
    for (int rr = 0; rr < 4; ++rr) {
        float s_ = Lpart[rr];
        #pragma unroll
        for (int off = 1; off < 16; off <<= 1)
            s_ += __shfl_xor(s_, off, 16);
        const int qg = qw0 + lh * 4 + rr;
        const int coob = (qg < 3 ? 3 - qg : 0) + (qg > 1021 ? qg - 1021 : 0);
        const float inv = 1.0f / (s_ + (float)coob);
        const int t = qg * 4 + r;
        float* orow = out + ((size_t)b * LSEQ + t) * DMODEL + h * DHEAD;
        #pragma unroll
        for (int j = 0; j < 4; ++j)
            orow[j * 16 + lr] = o[j][rr] * inv;
    }
}

extern "C" void kernel_launch(void* const* d_in, const int* in_sizes, int n_in,
                              void* d_out, int out_size, void* d_ws, size_t ws_size,
                              hipStream_t stream) {
    const float* x  = (const float*)d_in[0];
    const float* Wq = (const float*)d_in[1];
    const float* Wk = (const float*)d_in[2];
    const float* Wv = (const float*)d_in[3];
    float* out = (float*)d_out;

    const size_t SZ = (size_t)BATCH * NH * 4 * NPAD * DHEAD;   // per-tensor elems
    u16* Qb = (u16*)d_ws;
    u16* Kb = Qb + SZ;
    u16* Vb = Kb + SZ;

    // scratch for bf16 x and transposed W lives in d_out (overwritten by attn)
    u16* xb = (u16*)d_out;                       // 8192*512 u16
    u16* Wt = xb + (size_t)8192 * 512;           // 1536*512 u16

    prep_kernel<<<2304, 256, 0, stream>>>(x, Wq, Wk, Wv, xb, Wt, Kb, Vb);

    dim3 gg(64, 12);
    gemm_kernel<<<gg, 256, 0, stream>>>(xb, Wt, Qb, Kb, Vb);

    dim3 ga(64, 8);
    attn_kernel<<<ga, 512, 0, stream>>>(Qb, Kb, Vb, out);
}